// Round 4
// baseline (847.692 us; speedup 1.0000x reference)
//
#include <hip/hip_runtime.h>
#include <math.h>

#define N_NODES  100000
#define N_FEAT   128
#define N_HID    64
#define N_CLASS  10
#define N_GRAPHS 1000
#define N_EDGES  1600000
#define NTILES   1563      // ceil(100000/64)   (pre kernel, 64-node tiles)
#define BLK_N    128       // gather_mlp tile
#define NT2      782       // ceil(100000/128)
#define CSR_STRIDE 64      // fixed bucket per node; P(deg>=64)~1e-20 @ Poisson(16)
#define EMAX_LDS 32        // staged slots per node; P(deg>32)~1e-4 -> global tail

// bucketize: 128-node buckets, 8 concurrent XCD-affine dst-range groups
#define NBKT 782           // ceil(100000/128) == NT2 (bucket b == gather block b)
#define BCAP 3072          // Poisson(2048), sigma~45 -> +22 sigma; impossible to hit
#define BKT_PER_GRP 98     // ceil(782/8)
#define BKT_BLOCKS 2048

typedef int iv4 __attribute__((ext_vector_type(4)));

// ---- bf16 helpers: h stored bf16 (row = 128 B); all arithmetic fp32.
__device__ __forceinline__ float bflo(unsigned u) { return __uint_as_float(u << 16); }
__device__ __forceinline__ float bfhi(unsigned u) { return __uint_as_float(u & 0xffff0000u); }
__device__ __forceinline__ unsigned bf_rne(float f) {
    unsigned u = __float_as_uint(f);
    return (u + 0x7fffu + ((u >> 16) & 1u)) >> 16;
}
__device__ __forceinline__ unsigned pack2(float a, float b) {
    return bf_rne(a) | (bf_rne(b) << 16);
}

// ---- pre: h0 = x @ pre_w + pre_b (bf16 out). 64-node tile, K in two halves,
// 34.8 KB LDS, 4 blocks/CU.
__global__ __launch_bounds__(256, 4) void pre_kernel(
    const float* __restrict__ x, const float* __restrict__ W,
    const float* __restrict__ b, uint2* __restrict__ h)
{
    __shared__ float xs[64][68];
    __shared__ float ws[64][68];
    const int tid = threadIdx.x;
    const int tx = tid & 15, ty = tid >> 4;
    const int n0 = blockIdx.x * 64;

    float acc[4][4];
#pragma unroll
    for (int i = 0; i < 4; ++i)
#pragma unroll
        for (int j = 0; j < 4; ++j) acc[i][j] = 0.f;

    for (int p = 0; p < 2; ++p) {
        __syncthreads();
#pragma unroll
        for (int t = 0; t < 4; ++t) {
            const int idx = t * 256 + tid;
            const int m = idx >> 4, kv = idx & 15;
            float4 v = make_float4(0.f, 0.f, 0.f, 0.f);
            if (n0 + m < N_NODES)
                v = *(const float4*)(x + (size_t)(n0 + m) * N_FEAT + p * 64 + kv * 4);
            *(float4*)&xs[m][kv * 4] = v;
            *(float4*)&ws[m][kv * 4] =
                *(const float4*)(W + (size_t)(p * 64 + m) * N_HID + kv * 4);
        }
        __syncthreads();
#pragma unroll 2
        for (int k4 = 0; k4 < 16; ++k4) {
            float4 a[4], bb[4];
#pragma unroll
            for (int i = 0; i < 4; ++i)
                a[i] = *(const float4*)&xs[ty + 16 * i][k4 * 4];
#pragma unroll
            for (int j = 0; j < 4; ++j)
                bb[j] = *(const float4*)&ws[k4 * 4 + j][tx * 4];
#pragma unroll
            for (int i = 0; i < 4; ++i) {
                const float* ap = (const float*)&a[i];
#pragma unroll
                for (int j = 0; j < 4; ++j) {
                    const float* bp = (const float*)&bb[j];
#pragma unroll
                    for (int c = 0; c < 4; ++c)
                        acc[i][c] = fmaf(ap[j], bp[c], acc[i][c]);
                }
            }
        }
    }

    const float4 bias = *(const float4*)(b + tx * 4);
#pragma unroll
    for (int i = 0; i < 4; ++i) {
        const int node = n0 + ty + 16 * i;
        if (node < N_NODES) {
            h[(size_t)node * 16 + tx] = make_uint2(
                pack2(acc[i][0] + bias.x, acc[i][1] + bias.y),
                pack2(acc[i][2] + bias.z, acc[i][3] + bias.w));
        }
    }
}

// ---- bucketize (hist v4 phase 1): append each edge to its dst-bucket
// (128 nodes/bucket, 782 buckets). v1-v3 lesson: per-NODE scatter never
// merges in L2 because a node's ~16 slot writes spread over the whole scan
// (frontier 12.5K lines/XCD, must survive ~77us -> 5-6 writebacks/line).
// Sequential per-BUCKET appends shrink the frontier to ~98 lines/XCD (6 KB)
// and each 64 B line fills completely in ~1/128 of the kernel -> write
// amplification ~1. Edge packs to 4 B: (src<<7)|(dst&127), src<2^17.
// dst/src reads are plain (cached): the 8-group concurrent rescan hits L3
// (v1 measured FETCH 18 MB when cached). Group r = blockIdx&7 = XCD id owns
// buckets [r*98, r*98+98) so each bucket's cursor + frontier live in one L2.
__global__ __launch_bounds__(256) void bucketize_kernel(
    const int* __restrict__ ei, int* __restrict__ cur, int* __restrict__ bkt)
{
    const int r    = blockIdx.x & 7;
    const int g    = blockIdx.x >> 3;
    const int base = r * BKT_PER_GRP;
    const int gsz  = (gridDim.x >> 3) * blockDim.x;
    const int t0   = g * blockDim.x + threadIdx.x;
    const int4* dst4 = (const int4*)(ei + N_EDGES);
    for (int q = t0; q < N_EDGES / 4; q += gsz) {
        const int4 d = dst4[q];
        const int e0 = q * 4;
        int b = d.x >> 7;
        if ((unsigned)(b - base) < (unsigned)BKT_PER_GRP) {
            const int pos = atomicAdd(&cur[b], 1);
            if (pos < BCAP)
                bkt[(size_t)b * BCAP + pos] = (ei[e0] << 7) | (d.x & 127);
        }
        b = d.y >> 7;
        if ((unsigned)(b - base) < (unsigned)BKT_PER_GRP) {
            const int pos = atomicAdd(&cur[b], 1);
            if (pos < BCAP)
                bkt[(size_t)b * BCAP + pos] = (ei[e0 + 1] << 7) | (d.y & 127);
        }
        b = d.z >> 7;
        if ((unsigned)(b - base) < (unsigned)BKT_PER_GRP) {
            const int pos = atomicAdd(&cur[b], 1);
            if (pos < BCAP)
                bkt[(size_t)b * BCAP + pos] = (ei[e0 + 2] << 7) | (d.z & 127);
        }
        b = d.w >> 7;
        if ((unsigned)(b - base) < (unsigned)BKT_PER_GRP) {
            const int pos = atomicAdd(&cur[b], 1);
            if (pos < BCAP)
                bkt[(size_t)b * BCAP + pos] = (ei[e0 + 3] << 7) | (d.w & 127);
        }
    }
}

// ---- csr_build (hist v4 phase 2): one block per bucket (= per 128 nodes =
// per gather tile). Counting-sort the bucket's ~2048 packed entries into a
// 128x64 LDS CSR tile, then write CSR + deg fully coalesced (int4 stores).
// Slots >= deg hold garbage -- never dereferenced by gather (clamp reads).
__global__ __launch_bounds__(256) void csr_build_kernel(
    const int* __restrict__ bkt, const int* __restrict__ cur,
    int* __restrict__ csr, int* __restrict__ deg)
{
    __shared__ int lcsr[128][64];
    __shared__ int lcnt[128];
    const int b = blockIdx.x;
    const int tid = threadIdx.x;
    if (tid < 128) lcnt[tid] = 0;
    __syncthreads();

    int cnt = cur[b];
    if (cnt > BCAP) cnt = BCAP;
    const int* bp = bkt + (size_t)b * BCAP;
    for (int i = tid; i < cnt; i += 256) {
        const int v = bp[i];
        const int local = v & 127;
        const int p = atomicAdd(&lcnt[local], 1);
        if (p < CSR_STRIDE) lcsr[local][p] = v >> 7;
    }
    __syncthreads();

    const int n0 = b * 128;
    for (int t = tid; t < 128 * (CSR_STRIDE / 4); t += 256) {   // 2048 int4
        const int node = t >> 4, q = t & 15;
        if (n0 + node < N_NODES)
            *(int4*)(csr + (size_t)(n0 + node) * CSR_STRIDE + q * 4) =
                *(const int4*)&lcsr[node][q * 4];
    }
    if (tid < 128 && n0 + tid < N_NODES) deg[n0 + tid] = lcnt[tid];
}

// ---- fused GIN layer v4: 8-deep pipelined gather + fp32 2-GEMM MLP.
__global__ __launch_bounds__(512, 6) void gather_mlp_kernel(
    const uint2* __restrict__ hin, uint2* __restrict__ hout,
    const int* __restrict__ csr, const int* __restrict__ deg,
    const float* __restrict__ W1, const float* __restrict__ b1,
    const float* __restrict__ W2, const float* __restrict__ b2)
{
    __shared__ float as[BLK_N][68];   // [r][36..67] = staged eidx, then agg/z tile
    __shared__ float ws[64][68];      // W1, then W2
    __shared__ int   sdeg[BLK_N];
    const int tid = threadIdx.x;
    const int tx = tid & 15, ty = tid >> 4;   // ty = group id 0..31
    const int sub = tx;
    const int n0 = blockIdx.x * BLK_N;

    // stage W1 (latency hidden behind gather)
#pragma unroll
    for (int t = 0; t < 2; ++t) {
        const int idx = t * 512 + tid;
        const int m = idx >> 4, kv = idx & 15;
        *(float4*)&ws[m][kv * 4] = *(const float4*)(W1 + (size_t)m * N_HID + kv * 4);
    }
    // stage deg
    if (tid < BLK_N) {
        const int node = n0 + tid;
        sdeg[tid] = (node < N_NODES) ? deg[node] : 0;
    }
    // stage edge indices: first 32 slots per node -> as[r][36..67]
#pragma unroll
    for (int t = 0; t < 2; ++t) {
        const int idx = t * 512 + tid;        // 0..1023
        const int r = idx >> 3, s4 = idx & 7;
        const int node = n0 + r;
        int4 v = make_int4(0, 0, 0, 0);
        if (node < N_NODES)
            v = *(const int4*)(csr + (size_t)node * CSR_STRIDE + s4 * 4);
        *(int4*)((int*)&as[r][36] + s4 * 4) = v;
    }
    __syncthreads();

    // gather: group ty handles rows ty, ty+32, ty+64, ty+96
    for (int rep = 0; rep < 4; ++rep) {
        const int r = ty + 32 * rep;
        const int node = n0 + r;
        float ax = 0.f, ay = 0.f, az = 0.f, aw = 0.f;
        float bx = 0.f, by = 0.f, bz = 0.f, bw = 0.f;
        if (node < N_NODES) {
            int n = sdeg[r];
            n = n > CSR_STRIDE ? CSR_STRIDE : n;
            const uint2 a0 = hin[(size_t)node * 16 + sub];   // self term
            ax = bflo(a0.x); ay = bfhi(a0.x);
            az = bflo(a0.y); aw = bfhi(a0.y);
            const int nn = n > EMAX_LDS ? EMAX_LDS : n;
            const int* eptr = (const int*)&as[r][36];
            if (nn > 0) {
                for (int eb = 0; eb < nn; eb += 8) {   // 8 loads in flight
                    uint2 rv[8];
#pragma unroll
                    for (int u = 0; u < 8; ++u) {
                        const int idx = eb + u;
                        const int cl = idx < nn ? idx : nn - 1;  // clamp: slots>=deg are poison
                        rv[u] = hin[(size_t)eptr[cl] * 16 + sub];
                    }
#pragma unroll
                    for (int u = 0; u < 8; u += 2) {
                        if (eb + u < nn) {
                            ax += bflo(rv[u].x); ay += bfhi(rv[u].x);
                            az += bflo(rv[u].y); aw += bfhi(rv[u].y);
                        }
                        if (eb + u + 1 < nn) {
                            bx += bflo(rv[u + 1].x); by += bfhi(rv[u + 1].x);
                            bz += bflo(rv[u + 1].y); bw += bfhi(rv[u + 1].y);
                        }
                    }
                }
            }
            for (int t = EMAX_LDS; t < n; ++t) { // rare tail (P~1e-4)
                const int s0 = csr[(size_t)node * CSR_STRIDE + t];
                const uint2 a = hin[(size_t)s0 * 16 + sub];
                ax += bflo(a.x); ay += bfhi(a.x);
                az += bflo(a.y); aw += bfhi(a.y);
            }
        }
        // write result row (overlaps this row's eidx region — reads done)
        *(float4*)&as[r][sub * 4] =
            make_float4(ax + bx, ay + by, az + bz, aw + bw);
    }
    __syncthreads();

    // phase 1: z = relu(agg @ W1 + b1); rows ty + 32*i
    float acc[4][4];
#pragma unroll
    for (int i = 0; i < 4; ++i)
#pragma unroll
        for (int j = 0; j < 4; ++j) acc[i][j] = 0.f;
#pragma unroll 2
    for (int k4 = 0; k4 < 16; ++k4) {
        float4 a[4], bb[4];
#pragma unroll
        for (int i = 0; i < 4; ++i)
            a[i] = *(const float4*)&as[ty + 32 * i][k4 * 4];
#pragma unroll
        for (int j = 0; j < 4; ++j)
            bb[j] = *(const float4*)&ws[k4 * 4 + j][tx * 4];
#pragma unroll
        for (int i = 0; i < 4; ++i) {
            const float* ap = (const float*)&a[i];
#pragma unroll
            for (int j = 0; j < 4; ++j) {
                const float* bp = (const float*)&bb[j];
#pragma unroll
                for (int c = 0; c < 4; ++c)
                    acc[i][c] = fmaf(ap[j], bp[c], acc[i][c]);
            }
        }
    }
    const float4 bias1 = *(const float4*)(b1 + tx * 4);
    float4 z[4];
#pragma unroll
    for (int i = 0; i < 4; ++i) {
        z[i].x = fmaxf(acc[i][0] + bias1.x, 0.f);
        z[i].y = fmaxf(acc[i][1] + bias1.y, 0.f);
        z[i].z = fmaxf(acc[i][2] + bias1.z, 0.f);
        z[i].w = fmaxf(acc[i][3] + bias1.w, 0.f);
    }
    __syncthreads();               // all phase-1 reads of as/ws done
#pragma unroll
    for (int i = 0; i < 4; ++i)
        *(float4*)&as[ty + 32 * i][tx * 4] = z[i];
#pragma unroll
    for (int t = 0; t < 2; ++t) {
        const int idx = t * 512 + tid;
        const int m = idx >> 4, kv = idx & 15;
        *(float4*)&ws[m][kv * 4] = *(const float4*)(W2 + (size_t)m * N_HID + kv * 4);
    }
    __syncthreads();

    // phase 2: h = relu(z @ W2 + b2), bf16 out
#pragma unroll
    for (int i = 0; i < 4; ++i)
#pragma unroll
        for (int j = 0; j < 4; ++j) acc[i][j] = 0.f;
#pragma unroll 2
    for (int k4 = 0; k4 < 16; ++k4) {
        float4 a[4], bb[4];
#pragma unroll
        for (int i = 0; i < 4; ++i)
            a[i] = *(const float4*)&as[ty + 32 * i][k4 * 4];
#pragma unroll
        for (int j = 0; j < 4; ++j)
            bb[j] = *(const float4*)&ws[k4 * 4 + j][tx * 4];
#pragma unroll
        for (int i = 0; i < 4; ++i) {
            const float* ap = (const float*)&a[i];
#pragma unroll
            for (int j = 0; j < 4; ++j) {
                const float* bp = (const float*)&bb[j];
#pragma unroll
                for (int c = 0; c < 4; ++c)
                    acc[i][c] = fmaf(ap[j], bp[c], acc[i][c]);
            }
        }
    }
    const float4 bias2 = *(const float4*)(b2 + tx * 4);
#pragma unroll
    for (int i = 0; i < 4; ++i) {
        const int node = n0 + ty + 32 * i;
        if (node < N_NODES) {
            hout[(size_t)node * 16 + tx] = make_uint2(
                pack2(fmaxf(acc[i][0] + bias2.x, 0.f),
                      fmaxf(acc[i][1] + bias2.y, 0.f)),
                pack2(fmaxf(acc[i][2] + bias2.z, 0.f),
                      fmaxf(acc[i][3] + bias2.w, 0.f)));
        }
    }
}

// ---- fused pool+head: block per graph; wave 0 finishes post/ro/log_softmax
// in-register from the pooled row. h is bf16. ----
__global__ __launch_bounds__(256) void pool_head_kernel(
    const unsigned short* __restrict__ h, const int* __restrict__ batch,
    const float* __restrict__ Wp, const float* __restrict__ bp,
    const float* __restrict__ Wr, const float* __restrict__ br,
    float* __restrict__ out)
{
    const int graph = blockIdx.x;
    int l = 0, r = N_NODES;
    while (l < r) { int m = (l + r) >> 1; if (batch[m] < graph) l = m + 1; else r = m; }
    const int lo = l;
    r = N_NODES;
    while (l < r) { int m = (l + r) >> 1; if (batch[m] < graph + 1) l = m + 1; else r = m; }
    const int hi = l;

    const int lane = threadIdx.x & 63;
    const int wave = threadIdx.x >> 6;
    float acc = 0.0f;
    for (int i = lo + wave; i < hi; i += 4)
        acc += __uint_as_float(((unsigned)h[(size_t)i * N_HID + lane]) << 16);
    __shared__ float sacc[4][N_HID];
    sacc[wave][lane] = acc;
    __syncthreads();
    if (wave != 0) return;

    const float gv = sacc[0][lane] + sacc[1][lane] + sacc[2][lane] + sacc[3][lane];
    float acc2 = bp[lane];
#pragma unroll
    for (int k = 0; k < N_HID; ++k) {
        const float gk = __int_as_float(
            __builtin_amdgcn_readlane(__float_as_int(gv), k));  // exec-ignoring
        acc2 = fmaf(gk, Wp[k * N_HID + lane], acc2);
    }
    const float y = fmaxf(acc2, 0.f);

    float logit = (lane < N_CLASS) ? br[lane] : 0.f;
#pragma unroll
    for (int k = 0; k < N_HID; ++k) {
        const float yk = __int_as_float(
            __builtin_amdgcn_readlane(__float_as_int(y), k));
        if (lane < N_CLASS)
            logit = fmaf(yk, Wr[k * N_CLASS + lane], logit);
    }

    __shared__ float slog[N_CLASS];
    if (lane < N_CLASS) slog[lane] = logit;
    if (lane < N_CLASS) {
        float m = -INFINITY;
#pragma unroll
        for (int c = 0; c < N_CLASS; ++c) m = fmaxf(m, slog[c]);
        float sum = 0.0f;
#pragma unroll
        for (int c = 0; c < N_CLASS; ++c) sum += expf(slog[c] - m);
        out[(size_t)graph * N_CLASS + lane] = logit - m - logf(sum);
    }
}

extern "C" void kernel_launch(void* const* d_in, const int* in_sizes, int n_in,
                              void* d_out, int out_size, void* d_ws, size_t ws_size,
                              hipStream_t stream)
{
    const float* x       = (const float*)d_in[0];
    const int*   ei      = (const int*)d_in[1];   // [2, E]: row0=src, row1=dst
    const int*   batch   = (const int*)d_in[2];
    const float* pre_w   = (const float*)d_in[3];
    const float* pre_b   = (const float*)d_in[4];
    const float* conv_w1 = (const float*)d_in[5];
    const float* conv_b1 = (const float*)d_in[6];
    const float* conv_w2 = (const float*)d_in[7];
    const float* conv_b2 = (const float*)d_in[8];
    const float* post_w  = (const float*)d_in[9];
    const float* post_b  = (const float*)d_in[10];
    const float* ro_w    = (const float*)d_in[11];
    const float* ro_b    = (const float*)d_in[12];
    float* out = (float*)d_out;

    // workspace layout (~51.6 MB)
    uint2* h0   = (uint2*)d_ws;                       // 12.8 MB (bf16 h)
    uint2* h1   = h0 + (size_t)N_NODES * 16;          // 12.8 MB
    int*   deg  = (int*)(h1 + (size_t)N_NODES * 16);  // 400 KB
    int*   csr  = deg + N_NODES;                      // 25.6 MB fixed-stride
    int*   cur  = csr + (size_t)N_NODES * CSR_STRIDE; // 3.1 KB bucket cursors
    int*   bkt  = (int*)h1;                           // 9.4 MB, aliases h1:
    // buckets live only between bucketize and csr_build; h1 is first written
    // by gather layer 1, which runs after csr_build has consumed them.

    (void)hipMemsetAsync(cur, 0, NBKT * sizeof(int), stream);

    pre_kernel<<<NTILES, 256, 0, stream>>>(x, pre_w, pre_b, h0);
    bucketize_kernel<<<BKT_BLOCKS, 256, 0, stream>>>(ei, cur, bkt);
    csr_build_kernel<<<NBKT, 256, 0, stream>>>(bkt, cur, csr, deg);

    // 3 fused GIN layers, h ping-pong h0 -> h1 -> h0 -> h1
    gather_mlp_kernel<<<NT2, 512, 0, stream>>>(
        h0, h1, csr, deg,
        conv_w1, conv_b1, conv_w2, conv_b2);
    gather_mlp_kernel<<<NT2, 512, 0, stream>>>(
        h1, h0, csr, deg,
        conv_w1 + N_HID * N_HID, conv_b1 + N_HID,
        conv_w2 + N_HID * N_HID, conv_b2 + N_HID);
    gather_mlp_kernel<<<NT2, 512, 0, stream>>>(
        h0, h1, csr, deg,
        conv_w1 + 2 * N_HID * N_HID, conv_b1 + 2 * N_HID,
        conv_w2 + 2 * N_HID * N_HID, conv_b2 + 2 * N_HID);

    pool_head_kernel<<<N_GRAPHS, 256, 0, stream>>>(
        (const unsigned short*)h1, batch, post_w, post_b, ro_w, ro_b, out);
}

// Round 5
// 402.280 us; speedup vs baseline: 2.1072x; 2.1072x over previous
//
#include <hip/hip_runtime.h>
#include <math.h>

#define N_NODES  100000
#define N_FEAT   128
#define N_HID    64
#define N_CLASS  10
#define N_GRAPHS 1000
#define N_EDGES  1600000
#define NTILES   1563      // ceil(100000/64)   (pre kernel, 64-node tiles)
#define BLK_N    128       // gather_mlp tile
#define NT2      782       // ceil(100000/128)
#define HF_GROUPS 8        // concurrent dst ranges, one per XCD
#define HF_RANGE 12500     // 100000/8; csr window 3.2 MB < 4 MB/XCD L2
#define HF_BLOCKS 2048     // 8 blocks/CU resident (8 VGPR, 0 LDS)
#define CSR_STRIDE 64      // fixed bucket per node; P(deg>=64)~1e-20 @ Poisson(16)
#define EMAX_LDS 32        // staged slots per node; P(deg>32)~1e-4 -> global tail

typedef int iv4 __attribute__((ext_vector_type(4)));  // true vector type for nontemporal builtin

// ---- bf16 helpers: h stored bf16 (row = 128 B); all arithmetic fp32.
__device__ __forceinline__ float bflo(unsigned u) { return __uint_as_float(u << 16); }
__device__ __forceinline__ float bfhi(unsigned u) { return __uint_as_float(u & 0xffff0000u); }
__device__ __forceinline__ unsigned bf_rne(float f) {
    unsigned u = __float_as_uint(f);
    return (u + 0x7fffu + ((u >> 16) & 1u)) >> 16;
}
__device__ __forceinline__ unsigned pack2(float a, float b) {
    return bf_rne(a) | (bf_rne(b) << 16);
}

// ---- pre: h0 = x @ pre_w + pre_b (bf16 out). 64-node tile, K in two halves,
// 34.8 KB LDS, 4 blocks/CU.
__global__ __launch_bounds__(256, 4) void pre_kernel(
    const float* __restrict__ x, const float* __restrict__ W,
    const float* __restrict__ b, uint2* __restrict__ h)
{
    __shared__ float xs[64][68];
    __shared__ float ws[64][68];
    const int tid = threadIdx.x;
    const int tx = tid & 15, ty = tid >> 4;
    const int n0 = blockIdx.x * 64;

    float acc[4][4];
#pragma unroll
    for (int i = 0; i < 4; ++i)
#pragma unroll
        for (int j = 0; j < 4; ++j) acc[i][j] = 0.f;

    for (int p = 0; p < 2; ++p) {
        __syncthreads();
#pragma unroll
        for (int t = 0; t < 4; ++t) {
            const int idx = t * 256 + tid;
            const int m = idx >> 4, kv = idx & 15;
            float4 v = make_float4(0.f, 0.f, 0.f, 0.f);
            if (n0 + m < N_NODES)
                v = *(const float4*)(x + (size_t)(n0 + m) * N_FEAT + p * 64 + kv * 4);
            *(float4*)&xs[m][kv * 4] = v;
            *(float4*)&ws[m][kv * 4] =
                *(const float4*)(W + (size_t)(p * 64 + m) * N_HID + kv * 4);
        }
        __syncthreads();
#pragma unroll 2
        for (int k4 = 0; k4 < 16; ++k4) {
            float4 a[4], bb[4];
#pragma unroll
            for (int i = 0; i < 4; ++i)
                a[i] = *(const float4*)&xs[ty + 16 * i][k4 * 4];
#pragma unroll
            for (int j = 0; j < 4; ++j)
                bb[j] = *(const float4*)&ws[k4 * 4 + j][tx * 4];
#pragma unroll
            for (int i = 0; i < 4; ++i) {
                const float* ap = (const float*)&a[i];
#pragma unroll
                for (int j = 0; j < 4; ++j) {
                    const float* bp = (const float*)&bb[j];
#pragma unroll
                    for (int c = 0; c < 4; ++c)
                        acc[i][c] = fmaf(ap[j], bp[c], acc[i][c]);
                }
            }
        }
    }

    const float4 bias = *(const float4*)(b + tx * 4);
#pragma unroll
    for (int i = 0; i < 4; ++i) {
        const int node = n0 + ty + 16 * i;
        if (node < N_NODES) {
            h[(size_t)node * 16 + tx] = make_uint2(
                pack2(acc[i][0] + bias.x, acc[i][1] + bias.y),
                pack2(acc[i][2] + bias.z, acc[i][3] + bias.w));
        }
    }
}

// ---- hist+fill v3 (REVERTED from v4 bucketize): 8 concurrent dst-ranges
// with XCD affinity, NT dst+src reads. Measured 76.5us. v4 lesson (705us!):
// concentrating the 1.6M returning-atomics onto 782 cursors (~49 cache
// lines) serializes at the coherence point (~33K same-line atomics x ~50cy
// = 1.7M cycles). Keep atomics spread over 100K deg addresses. v1-v3 write
// patterns (92/79/66 MB) all landed 77-86us -> hist is near the returning-
// atomic throughput floor (~50 atomics/cycle chip-wide), not write-bound.
__global__ __launch_bounds__(256) void hist_fill_kernel(
    const int* __restrict__ ei, int* __restrict__ deg, int* __restrict__ csr)
{
    const int r   = blockIdx.x & (HF_GROUPS - 1);   // dst range == XCD id
    const int g   = blockIdx.x >> 3;                // block within group
    const int lo  = r * HF_RANGE;
    const int hi  = lo + HF_RANGE;
    const int gsz = (gridDim.x >> 3) * blockDim.x;  // threads per group
    const int t0  = g * blockDim.x + threadIdx.x;
    const iv4* dst4 = (const iv4*)(ei + N_EDGES);
    for (int q = t0; q < N_EDGES / 4; q += gsz) {
        const iv4 d = __builtin_nontemporal_load(dst4 + q);
        const int e0 = q * 4;
        if (d.x >= lo && d.x < hi) {
            int p = atomicAdd(&deg[d.x], 1);
            if (p < CSR_STRIDE)
                csr[d.x * CSR_STRIDE + p] = __builtin_nontemporal_load(ei + e0);
        }
        if (d.y >= lo && d.y < hi) {
            int p = atomicAdd(&deg[d.y], 1);
            if (p < CSR_STRIDE)
                csr[d.y * CSR_STRIDE + p] = __builtin_nontemporal_load(ei + e0 + 1);
        }
        if (d.z >= lo && d.z < hi) {
            int p = atomicAdd(&deg[d.z], 1);
            if (p < CSR_STRIDE)
                csr[d.z * CSR_STRIDE + p] = __builtin_nontemporal_load(ei + e0 + 2);
        }
        if (d.w >= lo && d.w < hi) {
            int p = atomicAdd(&deg[d.w], 1);
            if (p < CSR_STRIDE)
                csr[d.w * CSR_STRIDE + p] = __builtin_nontemporal_load(ei + e0 + 3);
        }
    }
}

// ---- fused GIN layer v5: paired-row gather (16 loads in flight per 16-lane
// group) + fp32 2-GEMM MLP. v4 held 8 loads in flight but processed the 4
// rows serially -> a deg-16 row pair costs 4 serial L2/L3 round-trips. v5
// issues both rows' 8-load batches before consuming either, halving the
// serial-latency chain per pair. Register cost ~+16 VGPR (budget ~85 at
// launch_bounds(512,6)).
__global__ __launch_bounds__(512, 6) void gather_mlp_kernel(
    const uint2* __restrict__ hin, uint2* __restrict__ hout,
    const int* __restrict__ csr, const int* __restrict__ deg,
    const float* __restrict__ W1, const float* __restrict__ b1,
    const float* __restrict__ W2, const float* __restrict__ b2)
{
    __shared__ float as[BLK_N][68];   // [r][36..67] = staged eidx, then agg/z tile
    __shared__ float ws[64][68];      // W1, then W2
    __shared__ int   sdeg[BLK_N];
    const int tid = threadIdx.x;
    const int tx = tid & 15, ty = tid >> 4;   // ty = group id 0..31
    const int sub = tx;
    const int n0 = blockIdx.x * BLK_N;

    // stage W1 (latency hidden behind gather)
#pragma unroll
    for (int t = 0; t < 2; ++t) {
        const int idx = t * 512 + tid;
        const int m = idx >> 4, kv = idx & 15;
        *(float4*)&ws[m][kv * 4] = *(const float4*)(W1 + (size_t)m * N_HID + kv * 4);
    }
    // stage deg
    if (tid < BLK_N) {
        const int node = n0 + tid;
        sdeg[tid] = (node < N_NODES) ? deg[node] : 0;
    }
    // stage edge indices: first 32 slots per node -> as[r][36..67]
#pragma unroll
    for (int t = 0; t < 2; ++t) {
        const int idx = t * 512 + tid;        // 0..1023
        const int r = idx >> 3, s4 = idx & 7;
        const int node = n0 + r;
        int4 v = make_int4(0, 0, 0, 0);
        if (node < N_NODES)
            v = *(const int4*)(csr + (size_t)node * CSR_STRIDE + s4 * 4);
        *(int4*)((int*)&as[r][36] + s4 * 4) = v;
    }
    __syncthreads();

    // gather: group ty owns rows ty, ty+32, ty+64, ty+96; processed as pairs
    // (rA, rB=rA+32) with both rows' loads in flight simultaneously.
    for (int pp = 0; pp < 2; ++pp) {
        const int rA = ty + 64 * pp;
        const int rB = rA + 32;
        const int nodeA = n0 + rA;
        const int nodeB = n0 + rB;
        float aAx = 0.f, aAy = 0.f, aAz = 0.f, aAw = 0.f;
        float bAx = 0.f, bAy = 0.f, bAz = 0.f, bAw = 0.f;
        float aBx = 0.f, aBy = 0.f, aBz = 0.f, aBw = 0.f;
        float bBx = 0.f, bBy = 0.f, bBz = 0.f, bBw = 0.f;
        int nA = 0, nB = 0;
        if (nodeA < N_NODES) {
            nA = sdeg[rA]; nA = nA > CSR_STRIDE ? CSR_STRIDE : nA;
            const uint2 s = hin[(size_t)nodeA * 16 + sub];   // self term
            aAx = bflo(s.x); aAy = bfhi(s.x); aAz = bflo(s.y); aAw = bfhi(s.y);
        }
        if (nodeB < N_NODES) {
            nB = sdeg[rB]; nB = nB > CSR_STRIDE ? CSR_STRIDE : nB;
            const uint2 s = hin[(size_t)nodeB * 16 + sub];   // self term
            aBx = bflo(s.x); aBy = bfhi(s.x); aBz = bflo(s.y); aBw = bfhi(s.y);
        }
        const int nnA = nA > EMAX_LDS ? EMAX_LDS : nA;
        const int nnB = nB > EMAX_LDS ? EMAX_LDS : nB;
        const int* epA = (const int*)&as[rA][36];
        const int* epB = (const int*)&as[rB][36];
        const int mx = nnA > nnB ? nnA : nnB;
        for (int eb = 0; eb < mx; eb += 8) {
            uint2 rvA[8], rvB[8];
            const bool doA = eb < nnA;
            const bool doB = eb < nnB;
            if (doA) {
#pragma unroll
                for (int u = 0; u < 8; ++u) {
                    const int idx = eb + u;
                    const int cl = idx < nnA ? idx : nnA - 1;  // clamp: slots>=deg are poison
                    rvA[u] = hin[(size_t)epA[cl] * 16 + sub];
                }
            }
            if (doB) {
#pragma unroll
                for (int u = 0; u < 8; ++u) {
                    const int idx = eb + u;
                    const int cl = idx < nnB ? idx : nnB - 1;
                    rvB[u] = hin[(size_t)epB[cl] * 16 + sub];
                }
            }
            if (doA) {
#pragma unroll
                for (int u = 0; u < 8; u += 2) {
                    if (eb + u < nnA) {
                        aAx += bflo(rvA[u].x); aAy += bfhi(rvA[u].x);
                        aAz += bflo(rvA[u].y); aAw += bfhi(rvA[u].y);
                    }
                    if (eb + u + 1 < nnA) {
                        bAx += bflo(rvA[u + 1].x); bAy += bfhi(rvA[u + 1].x);
                        bAz += bflo(rvA[u + 1].y); bAw += bfhi(rvA[u + 1].y);
                    }
                }
            }
            if (doB) {
#pragma unroll
                for (int u = 0; u < 8; u += 2) {
                    if (eb + u < nnB) {
                        aBx += bflo(rvB[u].x); aBy += bfhi(rvB[u].x);
                        aBz += bflo(rvB[u].y); aBw += bfhi(rvB[u].y);
                    }
                    if (eb + u + 1 < nnB) {
                        bBx += bflo(rvB[u + 1].x); bBy += bfhi(rvB[u + 1].x);
                        bBz += bflo(rvB[u + 1].y); bBw += bfhi(rvB[u + 1].y);
                    }
                }
            }
        }
        for (int t = EMAX_LDS; t < nA; ++t) { // rare tail (P~1e-4)
            const int s0 = csr[(size_t)nodeA * CSR_STRIDE + t];
            const uint2 a = hin[(size_t)s0 * 16 + sub];
            aAx += bflo(a.x); aAy += bfhi(a.x);
            aAz += bflo(a.y); aAw += bfhi(a.y);
        }
        for (int t = EMAX_LDS; t < nB; ++t) {
            const int s0 = csr[(size_t)nodeB * CSR_STRIDE + t];
            const uint2 a = hin[(size_t)s0 * 16 + sub];
            aBx += bflo(a.x); aBy += bfhi(a.x);
            aBz += bflo(a.y); aBw += bfhi(a.y);
        }
        // write result rows (overlap these rows' eidx regions — reads done)
        *(float4*)&as[rA][sub * 4] =
            make_float4(aAx + bAx, aAy + bAy, aAz + bAz, aAw + bAw);
        *(float4*)&as[rB][sub * 4] =
            make_float4(aBx + bBx, aBy + bBy, aBz + bBz, aBw + bBw);
    }
    __syncthreads();

    // phase 1: z = relu(agg @ W1 + b1); rows ty + 32*i
    float acc[4][4];
#pragma unroll
    for (int i = 0; i < 4; ++i)
#pragma unroll
        for (int j = 0; j < 4; ++j) acc[i][j] = 0.f;
#pragma unroll 2
    for (int k4 = 0; k4 < 16; ++k4) {
        float4 a[4], bb[4];
#pragma unroll
        for (int i = 0; i < 4; ++i)
            a[i] = *(const float4*)&as[ty + 32 * i][k4 * 4];
#pragma unroll
        for (int j = 0; j < 4; ++j)
            bb[j] = *(const float4*)&ws[k4 * 4 + j][tx * 4];
#pragma unroll
        for (int i = 0; i < 4; ++i) {
            const float* ap = (const float*)&a[i];
#pragma unroll
            for (int j = 0; j < 4; ++j) {
                const float* bp = (const float*)&bb[j];
#pragma unroll
                for (int c = 0; c < 4; ++c)
                    acc[i][c] = fmaf(ap[j], bp[c], acc[i][c]);
            }
        }
    }
    const float4 bias1 = *(const float4*)(b1 + tx * 4);
    float4 z[4];
#pragma unroll
    for (int i = 0; i < 4; ++i) {
        z[i].x = fmaxf(acc[i][0] + bias1.x, 0.f);
        z[i].y = fmaxf(acc[i][1] + bias1.y, 0.f);
        z[i].z = fmaxf(acc[i][2] + bias1.z, 0.f);
        z[i].w = fmaxf(acc[i][3] + bias1.w, 0.f);
    }
    __syncthreads();               // all phase-1 reads of as/ws done
#pragma unroll
    for (int i = 0; i < 4; ++i)
        *(float4*)&as[ty + 32 * i][tx * 4] = z[i];
#pragma unroll
    for (int t = 0; t < 2; ++t) {
        const int idx = t * 512 + tid;
        const int m = idx >> 4, kv = idx & 15;
        *(float4*)&ws[m][kv * 4] = *(const float4*)(W2 + (size_t)m * N_HID + kv * 4);
    }
    __syncthreads();

    // phase 2: h = relu(z @ W2 + b2), bf16 out
#pragma unroll
    for (int i = 0; i < 4; ++i)
#pragma unroll
        for (int j = 0; j < 4; ++j) acc[i][j] = 0.f;
#pragma unroll 2
    for (int k4 = 0; k4 < 16; ++k4) {
        float4 a[4], bb[4];
#pragma unroll
        for (int i = 0; i < 4; ++i)
            a[i] = *(const float4*)&as[ty + 32 * i][k4 * 4];
#pragma unroll
        for (int j = 0; j < 4; ++j)
            bb[j] = *(const float4*)&ws[k4 * 4 + j][tx * 4];
#pragma unroll
        for (int i = 0; i < 4; ++i) {
            const float* ap = (const float*)&a[i];
#pragma unroll
            for (int j = 0; j < 4; ++j) {
                const float* bp = (const float*)&bb[j];
#pragma unroll
                for (int c = 0; c < 4; ++c)
                    acc[i][c] = fmaf(ap[j], bp[c], acc[i][c]);
            }
        }
    }
    const float4 bias2 = *(const float4*)(b2 + tx * 4);
#pragma unroll
    for (int i = 0; i < 4; ++i) {
        const int node = n0 + ty + 32 * i;
        if (node < N_NODES) {
            hout[(size_t)node * 16 + tx] = make_uint2(
                pack2(fmaxf(acc[i][0] + bias2.x, 0.f),
                      fmaxf(acc[i][1] + bias2.y, 0.f)),
                pack2(fmaxf(acc[i][2] + bias2.z, 0.f),
                      fmaxf(acc[i][3] + bias2.w, 0.f)));
        }
    }
}

// ---- fused pool+head: block per graph; wave 0 finishes post/ro/log_softmax
// in-register from the pooled row. h is bf16. ----
__global__ __launch_bounds__(256) void pool_head_kernel(
    const unsigned short* __restrict__ h, const int* __restrict__ batch,
    const float* __restrict__ Wp, const float* __restrict__ bp,
    const float* __restrict__ Wr, const float* __restrict__ br,
    float* __restrict__ out)
{
    const int graph = blockIdx.x;
    int l = 0, r = N_NODES;
    while (l < r) { int m = (l + r) >> 1; if (batch[m] < graph) l = m + 1; else r = m; }
    const int lo = l;
    r = N_NODES;
    while (l < r) { int m = (l + r) >> 1; if (batch[m] < graph + 1) l = m + 1; else r = m; }
    const int hi = l;

    const int lane = threadIdx.x & 63;
    const int wave = threadIdx.x >> 6;
    float acc = 0.0f;
    for (int i = lo + wave; i < hi; i += 4)
        acc += __uint_as_float(((unsigned)h[(size_t)i * N_HID + lane]) << 16);
    __shared__ float sacc[4][N_HID];
    sacc[wave][lane] = acc;
    __syncthreads();
    if (wave != 0) return;

    const float gv = sacc[0][lane] + sacc[1][lane] + sacc[2][lane] + sacc[3][lane];
    float acc2 = bp[lane];
#pragma unroll
    for (int k = 0; k < N_HID; ++k) {
        const float gk = __int_as_float(
            __builtin_amdgcn_readlane(__float_as_int(gv), k));  // exec-ignoring
        acc2 = fmaf(gk, Wp[k * N_HID + lane], acc2);
    }
    const float y = fmaxf(acc2, 0.f);

    float logit = (lane < N_CLASS) ? br[lane] : 0.f;
#pragma unroll
    for (int k = 0; k < N_HID; ++k) {
        const float yk = __int_as_float(
            __builtin_amdgcn_readlane(__float_as_int(y), k));
        if (lane < N_CLASS)
            logit = fmaf(yk, Wr[k * N_CLASS + lane], logit);
    }

    __shared__ float slog[N_CLASS];
    if (lane < N_CLASS) slog[lane] = logit;
    if (lane < N_CLASS) {
        float m = -INFINITY;
#pragma unroll
        for (int c = 0; c < N_CLASS; ++c) m = fmaxf(m, slog[c]);
        float sum = 0.0f;
#pragma unroll
        for (int c = 0; c < N_CLASS; ++c) sum += expf(slog[c] - m);
        out[(size_t)graph * N_CLASS + lane] = logit - m - logf(sum);
    }
}

extern "C" void kernel_launch(void* const* d_in, const int* in_sizes, int n_in,
                              void* d_out, int out_size, void* d_ws, size_t ws_size,
                              hipStream_t stream)
{
    const float* x       = (const float*)d_in[0];
    const int*   ei      = (const int*)d_in[1];   // [2, E]: row0=src, row1=dst
    const int*   batch   = (const int*)d_in[2];
    const float* pre_w   = (const float*)d_in[3];
    const float* pre_b   = (const float*)d_in[4];
    const float* conv_w1 = (const float*)d_in[5];
    const float* conv_b1 = (const float*)d_in[6];
    const float* conv_w2 = (const float*)d_in[7];
    const float* conv_b2 = (const float*)d_in[8];
    const float* post_w  = (const float*)d_in[9];
    const float* post_b  = (const float*)d_in[10];
    const float* ro_w    = (const float*)d_in[11];
    const float* ro_b    = (const float*)d_in[12];
    float* out = (float*)d_out;

    // workspace layout (~51.6 MB)
    uint2* h0   = (uint2*)d_ws;                       // 12.8 MB (bf16 h)
    uint2* h1   = h0 + (size_t)N_NODES * 16;          // 12.8 MB
    int*   deg  = (int*)(h1 + (size_t)N_NODES * 16);  // 400 KB
    int*   csr  = deg + N_NODES;                      // 25.6 MB fixed-stride

    (void)hipMemsetAsync(deg, 0, N_NODES * sizeof(int), stream);

    pre_kernel<<<NTILES, 256, 0, stream>>>(x, pre_w, pre_b, h0);
    hist_fill_kernel<<<HF_BLOCKS, 256, 0, stream>>>(ei, deg, csr);

    // 3 fused GIN layers, h ping-pong h0 -> h1 -> h0 -> h1
    gather_mlp_kernel<<<NT2, 512, 0, stream>>>(
        h0, h1, csr, deg,
        conv_w1, conv_b1, conv_w2, conv_b2);
    gather_mlp_kernel<<<NT2, 512, 0, stream>>>(
        h1, h0, csr, deg,
        conv_w1 + N_HID * N_HID, conv_b1 + N_HID,
        conv_w2 + N_HID * N_HID, conv_b2 + N_HID);
    gather_mlp_kernel<<<NT2, 512, 0, stream>>>(
        h0, h1, csr, deg,
        conv_w1 + 2 * N_HID * N_HID, conv_b1 + 2 * N_HID,
        conv_w2 + 2 * N_HID * N_HID, conv_b2 + 2 * N_HID);

    pool_head_kernel<<<N_GRAPHS, 256, 0, stream>>>(
        (const unsigned short*)h1, batch, post_w, post_b, ro_w, ro_b, out);
}